// Round 14
// baseline (318.509 us; speedup 1.0000x reference)
//
#include <hip/hip_runtime.h>

#define B_ 2
#define S_ 2048
#define E_ 1024
#define H_ 16
#define DH_ 64
#define FF_ 4096

typedef unsigned short bf16_t;
typedef __attribute__((ext_vector_type(8))) short bfrag;
typedef __attribute__((ext_vector_type(4))) float f32x4;
typedef __attribute__((ext_vector_type(16))) float f32x16;
typedef __attribute__((ext_vector_type(4))) unsigned int u32x4;

__device__ __forceinline__ bf16_t f2bf(float x) {
  union { float f; unsigned u; } c; c.f = x;
  return (bf16_t)((c.u + 0x7fffu + ((c.u >> 16) & 1u)) >> 16);
}

__device__ __forceinline__ float bf2f(unsigned short u) {
  union { unsigned u; float f; } c; c.u = (unsigned)u << 16;
  return c.f;
}

__device__ __forceinline__ unsigned pkbf(float lo, float hi) {
  unsigned r;
  asm("v_cvt_pk_bf16_f32 %0, %1, %2" : "=v"(r) : "v"(lo), "v"(hi));
  return r;
}

__device__ __forceinline__ void gload16(const void* g, void* l) {
  __builtin_amdgcn_global_load_lds(
      (const __attribute__((address_space(1))) void*)g,
      (__attribute__((address_space(3))) void*)l, 16, 0, 0);
}

// ---- prep: 4 weight transposes (f32 -> bf16^T) + x f32->bf16 cvt, one grid ----
// bids: [0,3072) w_qkv | [3072,4096) w_proj | [4096,8192) w1 | [8192,12288) w2
//       | [12288,16384) x cvt
__global__ void prep_kernel(const float* __restrict__ s0, bf16_t* __restrict__ d0,
                            const float* __restrict__ s1, bf16_t* __restrict__ d1,
                            const float* __restrict__ s2, bf16_t* __restrict__ d2,
                            const float* __restrict__ s3, bf16_t* __restrict__ d3,
                            const float* __restrict__ xs, bf16_t* __restrict__ xd) {
  __shared__ float tile[32][33];
  const int bid = blockIdx.x;
  const int tx = threadIdx.x, ty = threadIdx.y;
  if (bid >= 12288) {
    const int i = (bid - 12288) * 256 + ty * 32 + tx;
    const float4 v = ((const float4*)xs)[i];
    union { bf16_t u[4]; uint2 uv; } o;
    o.u[0] = f2bf(v.x); o.u[1] = f2bf(v.y); o.u[2] = f2bf(v.z); o.u[3] = f2bf(v.w);
    *(uint2*)(xd + (size_t)i * 4) = o.uv;
    return;
  }
  const float* src; bf16_t* dst; int R, C, lid;
  if (bid < 3072)      { src = s0; dst = d0; R = 1024; C = 3072; lid = bid; }
  else if (bid < 4096) { src = s1; dst = d1; R = 1024; C = 1024; lid = bid - 3072; }
  else if (bid < 8192) { src = s2; dst = d2; R = 1024; C = 4096; lid = bid - 4096; }
  else                 { src = s3; dst = d3; R = 4096; C = 1024; lid = bid - 8192; }
  const int ncx = C >> 5;
  const int c0 = (lid % ncx) * 32, r0 = (lid / ncx) * 32;
#pragma unroll
  for (int i = 0; i < 32; i += 8)
    tile[ty + i][tx] = src[(size_t)(r0 + ty + i) * C + c0 + tx];
  __syncthreads();
#pragma unroll
  for (int i = 0; i < 32; i += 8)
    dst[(size_t)(c0 + ty + i) * R + r0 + tx] = f2bf(tile[tx][ty + i]);
}

// ---------------- V transpose per (b,h): [S][64] -> [64][S] bf16 ----------------
__global__ void vtrans_kernel(const bf16_t* __restrict__ qkv, bf16_t* __restrict__ vt) {
  const int bh = blockIdx.z;
  const int b = bh >> 4, h = bh & 15;
  const bf16_t* src = qkv + (size_t)b * S_ * 3 * E_ + (size_t)2 * H_ * S_ * DH_ +
                      (size_t)h * S_ * DH_;
  bf16_t* dst = vt + (size_t)bh * DH_ * S_;
  const int s0 = blockIdx.x * 32, d0 = blockIdx.y * 32;
  __shared__ bf16_t tile[32][33];
  const int tx = threadIdx.x, ty = threadIdx.y;
#pragma unroll
  for (int i = 0; i < 32; i += 8)
    tile[ty + i][tx] = src[(size_t)(s0 + ty + i) * DH_ + d0 + tx];
  __syncthreads();
#pragma unroll
  for (int i = 0; i < 32; i += 8)
    dst[(size_t)(d0 + ty + i) * S_ + s0 + tx] = tile[tx][ty + i];
}

// ================= 256x256 8-phase GEMM (m201 template, plain HIP) =============
// MODE 0: outB = bf16(acc + bias)            MODE 1: outF = acc + bias + resid
// MODE 2: outB = bf16(relu(acc + bias))      MODE 3: outF = acc + bias
// MODE 4: outB(partial z) = bf16(acc)        (split-K, bf16 partials)

__device__ __forceinline__ void stage_half(const bf16_t* __restrict__ G, int row0,
                                           int kbyte, int Kbytes, bf16_t* ldsreg,
                                           int w, int l) {
#pragma unroll
  for (int j = 0; j < 2; ++j) {
    const int chunk = j * 8 + w;                // wave-uniform
    const int r = chunk * 8 + (l >> 3);         // row within 128-row half (src only)
    const int slot = ((l & 7) ^ (r & 7)) << 4;  // pre-swizzled source slot
    const char* src = (const char*)G + (size_t)(row0 + r) * Kbytes + kbyte + slot;
    gload16(src, (char*)ldsreg + chunk * 1024);
  }
}

__device__ __forceinline__ bfrag ldfrag(const bf16_t* __restrict__ reg, int r, int ks,
                                        int l) {
  int cb = ks * 64 + ((l >> 4) << 4);
  cb ^= (r & 7) << 4;
  return *(const bfrag*)((const char*)reg + r * 128 + cb);
}

template <int MODE>
__global__ __launch_bounds__(512, 2) void gemm8(
    const bf16_t* __restrict__ A, const bf16_t* __restrict__ Bt,
    const float* __restrict__ bias, const float* __restrict__ resid,
    float* __restrict__ outF, bf16_t* __restrict__ outB,
    int M, int N, int K, int ktiles) {
  __shared__ __align__(16) bf16_t lds4[4][256 * 64];
  const int tid = threadIdx.x;
  const int w = tid >> 6, l = tid & 63;
  const int wr = (w >> 2) * 128, wc = (w & 3) * 64;
  const int m0t = blockIdx.y * 256, n0t = blockIdx.x * 256;
  const int Kb = K * 2;
  const int kt0 = (MODE == 4) ? (int)blockIdx.z * ktiles : 0;
  const int ktEnd = kt0 + ktiles;
  if (MODE == 4) outB += (size_t)blockIdx.z * (size_t)M * N;

  stage_half(A, m0t, kt0 * 128, Kb, lds4[0], w, l);
  stage_half(A, m0t + 128, kt0 * 128, Kb, lds4[0] + 8192, w, l);
  stage_half(Bt, n0t, kt0 * 128, Kb, lds4[1], w, l);
  stage_half(Bt, n0t + 128, kt0 * 128, Kb, lds4[1] + 8192, w, l);
  stage_half(Bt, n0t, (kt0 + 1) * 128, Kb, lds4[3], w, l);
  stage_half(Bt, n0t + 128, (kt0 + 1) * 128, Kb, lds4[3] + 8192, w, l);
  asm volatile("s_waitcnt vmcnt(4)" ::: "memory");
  __builtin_amdgcn_s_barrier();

  f32x4 acc[8][4] = {};
  const int fr = l & 15;

  for (int t2 = kt0; t2 < ktEnd; t2 += 2) {
#pragma unroll
    for (int d = 0; d < 2; ++d) {
      const bf16_t* Ar = lds4[d * 2];
      const bf16_t* Br = lds4[d * 2 + 1];
      int sa = t2 + 1 + d; if (sa >= ktEnd) sa = kt0;
      int sb = t2 + 2 + d; if (sb >= ktEnd) sb = kt0;
      bfrag bfr[4][2], afr[2][2];
#pragma unroll
      for (int p = 0; p < 4; ++p) {
        if (p == 0) {
#pragma unroll
          for (int n = 0; n < 4; ++n)
#pragma unroll
            for (int ks = 0; ks < 2; ++ks)
              bfr[n][ks] = ldfrag(Br, wc + n * 16 + fr, ks, l);
        }
#pragma unroll
        for (int mm = 0; mm < 2; ++mm)
#pragma unroll
          for (int ks = 0; ks < 2; ++ks)
            afr[mm][ks] = ldfrag(Ar, wr + p * 32 + mm * 16 + fr, ks, l);
        if (p == 0)      stage_half(A, m0t, sa * 128, Kb, lds4[(d ^ 1) * 2], w, l);
        else if (p == 1) stage_half(A, m0t + 128, sa * 128, Kb, lds4[(d ^ 1) * 2] + 8192, w, l);
        else if (p == 2) stage_half(Bt, n0t, sb * 128, Kb, lds4[d * 2 + 1], w, l);
        else             stage_half(Bt, n0t + 128, sb * 128, Kb, lds4[d * 2 + 1] + 8192, w, l);
        __builtin_amdgcn_s_barrier();
        asm volatile("s_waitcnt lgkmcnt(0)" ::: "memory");
        __builtin_amdgcn_sched_barrier(0);
        __builtin_amdgcn_s_setprio(1);
#pragma unroll
        for (int mm = 0; mm < 2; ++mm)
#pragma unroll
          for (int n = 0; n < 4; ++n)
#pragma unroll
            for (int ks = 0; ks < 2; ++ks)
              acc[p * 2 + mm][n] = __builtin_amdgcn_mfma_f32_16x16x32_bf16(
                  afr[mm][ks], bfr[n][ks], acc[p * 2 + mm][n], 0, 0, 0);
        __builtin_amdgcn_s_setprio(0);
        if (p == 3) asm volatile("s_waitcnt vmcnt(4)" ::: "memory");
        __builtin_amdgcn_s_barrier();
      }
    }
  }

  const int cr = (l >> 4) * 4, cc = l & 15;
#pragma unroll
  for (int n = 0; n < 4; ++n) {
    const int gc = n0t + wc + n * 16 + cc;
    const float bn = (MODE == 4) ? 0.f : bias[gc];
#pragma unroll
    for (int m = 0; m < 8; ++m) {
      const int gr0 = m0t + wr + m * 16 + cr;
#pragma unroll
      for (int j = 0; j < 4; ++j) {
        float v = acc[m][n][j] + bn;
        const size_t idx = (size_t)(gr0 + j) * N + gc;
        if (MODE == 1) v += resid[idx];
        if (MODE == 2) v = fmaxf(v, 0.f);
        if (MODE == 0 || MODE == 2 || MODE == 4) outB[idx] = f2bf(v);
        else outF[idx] = v;
      }
    }
  }
}

// ------ split-K reduce (bf16 partials): out = p0+p1+p2+p3 + bias (f32) ------
__global__ __launch_bounds__(256) void red4_kernel(const bf16_t* __restrict__ p,
                                                   const float* __restrict__ bias,
                                                   float* __restrict__ out) {
  const size_t i = ((size_t)blockIdx.x * 256 + threadIdx.x) * 4;
  const size_t PS = (size_t)4096 * 1024;
  float4 v = {0.f, 0.f, 0.f, 0.f};
#pragma unroll
  for (int z = 0; z < 4; ++z) {
    const ushort4 u = *(const ushort4*)(p + z * PS + i);
    v.x += bf2f(u.x); v.y += bf2f(u.y); v.z += bf2f(u.z); v.w += bf2f(u.w);
  }
  const float4 bb = *(const float4*)(bias + (i & 1023));
  v.x += bb.x; v.y += bb.y; v.z += bb.z; v.w += bb.w;
  *(float4*)(out + i) = v;
}

// ---------------- causal flash attention ----------------
// r12 inner structure; 2-wave blocks (128 thr), grid (32,32) over 64-row
// q-groups, zigzag pairing: finer retire granularity -> higher avg occupancy.
#define C1_ 0.0450842213f  // (1/32) * log2(e)

struct kf4 { bfrag k[4]; };

__device__ __forceinline__ kf4 loadK32(const bf16_t* __restrict__ Kp, int kv0,
                                       int lq32, int hi) {
  kf4 r;
#pragma unroll
  for (int c = 0; c < 4; ++c)
    r.k[c] = *(const bfrag*)&Kp[(size_t)(kv0 + lq32) * DH_ + c * 16 + hi * 8];
  return r;
}

template <bool MASK>
__device__ __forceinline__ void compute32(const kf4& s, const bf16_t* __restrict__ Vt,
                                          int kv0, const bfrag* qf, f32x16& o0,
                                          f32x16& o1, f32x16& lacc, float& m,
                                          int lq32, int hi) {
  const short onebf = (short)0x3F80;
  bfrag ones;
#pragma unroll
  for (int j = 0; j < 8; ++j) ones[j] = onebf;
  bfrag v00, v01, v10, v11;
  {
    const bf16_t* vr = &Vt[(size_t)lq32 * S_ + kv0 + hi * 8];
    v00 = *(const bfrag*)vr;
    v01 = *(const bfrag*)(vr + 16);
    const bf16_t* vr2 = &Vt[(size_t)(32 + lq32) * S_ + kv0 + hi * 8];
    v10 = *(const bfrag*)vr2;
    v11 = *(const bfrag*)(vr2 + 16);
  }
  f32x16 st;
#pragma unroll
  for (int j = 0; j < 16; ++j) st[j] = 0.f;
#pragma unroll
  for (int c = 0; c < 4; ++c)
    st = __builtin_amdgcn_mfma_f32_32x32x16_bf16(s.k[c], qf[c], st, 0, 0, 0);
  if (MASK) {
#pragma unroll
    for (int r = 0; r < 16; ++r) {
      const int kvloc = (r & 3) + 8 * (r >> 2) + 4 * hi;
      st[r] = (kvloc <= lq32) ? st[r] : -3.0e38f;
    }
  }
  float mx[8];
#pragma unroll
  for (int j = 0; j < 8; ++j) mx[j] = fmaxf(st[j], st[j + 8]);
#pragma unroll
  for (int stp = 4; stp >= 1; stp >>= 1)
#pragma unroll
    for (int j = 0; j < stp; ++j) mx[j] = fmaxf(mx[j], mx[j + stp]);
  float pm = fmaxf(mx[0], __shfl_xor(mx[0], 32));
  if (!__all(pm <= m + 128.0f)) {  // defer-max: P bounded by 2^(128*C1) ~ 54
    const float mn = fmaxf(m, pm);
    const float corr = exp2f((m - mn) * C1_);
    m = mn;
#pragma unroll
    for (int j = 0; j < 16; ++j) { o0[j] *= corr; o1[j] *= corr; lacc[j] *= corr; }
  }
  const float mc = m * C1_;
  float p[16];
#pragma unroll
  for (int j = 0; j < 16; ++j) p[j] = exp2f(__builtin_fmaf(st[j], C1_, -mc));
  unsigned wv[8], ov[8];
#pragma unroll
  for (int j = 0; j < 8; ++j) wv[j] = pkbf(p[2 * j], p[2 * j + 1]);
#pragma unroll
  for (int j = 0; j < 8; ++j) ov[j] = (unsigned)__shfl_xor((int)wv[j], 32);
  union { unsigned u[4]; bfrag f; } f0, f1;
  f0.u[0] = hi ? ov[2] : wv[0];  f0.u[1] = hi ? ov[3] : wv[1];
  f0.u[2] = hi ? wv[2] : ov[0];  f0.u[3] = hi ? wv[3] : ov[1];
  f1.u[0] = hi ? ov[6] : wv[4];  f1.u[1] = hi ? ov[7] : wv[5];
  f1.u[2] = hi ? wv[6] : ov[4];  f1.u[3] = hi ? wv[7] : ov[5];
  o0 = __builtin_amdgcn_mfma_f32_32x32x16_bf16(v00, f0.f, o0, 0, 0, 0);
  o1 = __builtin_amdgcn_mfma_f32_32x32x16_bf16(v10, f0.f, o1, 0, 0, 0);
  lacc = __builtin_amdgcn_mfma_f32_32x32x16_bf16(ones, f0.f, lacc, 0, 0, 0);
  o0 = __builtin_amdgcn_mfma_f32_32x32x16_bf16(v01, f1.f, o0, 0, 0, 0);
  o1 = __builtin_amdgcn_mfma_f32_32x32x16_bf16(v11, f1.f, o1, 0, 0, 0);
  lacc = __builtin_amdgcn_mfma_f32_32x32x16_bf16(ones, f1.f, lacc, 0, 0, 0);
}

__global__ __launch_bounds__(128, 4) void attn_kernel(const bf16_t* __restrict__ qkv,
                                                      const bf16_t* __restrict__ vt,
                                                      bf16_t* __restrict__ outp) {
  __shared__ unsigned short ot[2][32 * 72];
  const int tid = threadIdx.x;
  const int w = tid >> 6, l = tid & 63;
  const int lq32 = l & 31, hi = l >> 5;
  const int by = blockIdx.y;
  const int b = by >> 4, h = by & 15;
  const int x = blockIdx.x;  // 0..31, 64-row q-groups, zigzag pairs sum const
  const int qg = (x & 1) ? (31 - (x >> 1)) : (x >> 1);
  const size_t bbase = (size_t)b * S_ * 3 * E_;
  const bf16_t* Q = qkv + bbase + (size_t)h * S_ * DH_;
  const bf16_t* Kp = Q + (size_t)H_ * S_ * DH_;
  const bf16_t* Vt = vt + (size_t)by * DH_ * S_;
  bf16_t* Og = outp + (size_t)by * S_ * DH_;
  const int q0w = qg * 64 + w * 32;

  bfrag qf[4];
#pragma unroll
  for (int c = 0; c < 4; ++c)
    qf[c] = *(const bfrag*)&Q[(size_t)(q0w + lq32) * DH_ + c * 16 + hi * 8];

  f32x16 o0, o1, lacc;
#pragma unroll
  for (int j = 0; j < 16; ++j) { o0[j] = 0.f; o1[j] = 0.f; lacc[j] = 0.f; }
  float m = -3.0e38f;

  const int nsteps = q0w >> 5;  // full 32-kv steps before the diagonal
  kf4 kcur = loadK32(Kp, 0, lq32, hi);
  for (int s = 0; s < nsteps; ++s) {
    kf4 knxt = loadK32(Kp, (s + 1) * 32, lq32, hi);  // last iter = diagonal K
    compute32<false>(kcur, Vt, s * 32, qf, o0, o1, lacc, m, lq32, hi);
    kcur = knxt;
  }
  compute32<true>(kcur, Vt, q0w, qf, o0, o1, lacc, m, lq32, hi);

  // epilogue: O^T regs -> LDS [q][d] (stride 72) -> coalesced [s][d] global
  const float linv = 1.0f / lacc[0];
  unsigned short* otw = ot[w];
#pragma unroll
  for (int t = 0; t < 2; ++t) {
    const f32x16& oo = t ? o1 : o0;
#pragma unroll
    for (int g = 0; g < 4; ++g) {
      const int d = t * 32 + g * 8 + hi * 4;
      uint2 v;
      v.x = pkbf(oo[g * 4 + 0] * linv, oo[g * 4 + 1] * linv);
      v.y = pkbf(oo[g * 4 + 2] * linv, oo[g * 4 + 3] * linv);
      *(uint2*)&otw[lq32 * 72 + d] = v;
    }
  }
  asm volatile("s_waitcnt lgkmcnt(0)" ::: "memory");
  const int q = l >> 1, hh = l & 1;
#pragma unroll
  for (int i = 0; i < 4; ++i) {
    u32x4 v = *(const u32x4*)&otw[q * 72 + hh * 32 + i * 8];
    *(u32x4*)&Og[(size_t)(q0w + q) * DH_ + hh * 32 + i * 8] = v;
  }
}

// ---------------- LayerNorm (plain): f32 in -> bf16 ----------------
__device__ __forceinline__ void ln_core(float4 v, int t, const float* g,
                                        const float* be, bf16_t* orow) {
  float s = v.x + v.y + v.z + v.w;
  float q = v.x * v.x + v.y * v.y + v.z * v.z + v.w * v.w;
#pragma unroll
  for (int d = 1; d < 64; d <<= 1) { s += __shfl_xor(s, d); q += __shfl_xor(q, d); }
  __shared__ float red[8];
  const int w = t >> 6;
  if ((t & 63) == 0) { red[w] = s; red[4 + w] = q; }
  __syncthreads();
  s = red[0] + red[1] + red[2] + red[3];
  q = red[4] + red[5] + red[6] + red[7];
  const float mu = s * (1.f / E_);
  const float var = q * (1.f / E_) - mu * mu;
  const float rs = rsqrtf(var + 1e-5f);
  const float4 gg = ((const float4*)g)[t];
  const float4 bb = ((const float4*)be)[t];
  union { bf16_t u[4]; uint2 uv; } o;
  o.u[0] = f2bf((v.x - mu) * rs * gg.x + bb.x);
  o.u[1] = f2bf((v.y - mu) * rs * gg.y + bb.y);
  o.u[2] = f2bf((v.z - mu) * rs * gg.z + bb.z);
  o.u[3] = f2bf((v.w - mu) * rs * gg.w + bb.w);
  *(uint2*)(orow + t * 4) = o.uv;
}

__global__ __launch_bounds__(256) void ln_kernel(const float* __restrict__ hin,
                                                 const float* __restrict__ g,
                                                 const float* __restrict__ be,
                                                 bf16_t* __restrict__ outp) {
  const int row = blockIdx.x, t = threadIdx.x;
  const float4 v = ((const float4*)(hin + (size_t)row * E_))[t];
  ln_core(v, t, g, be, outp + (size_t)row * E_);
}

// -- LN fused with proj split-K(z=4) reduce (bf16 partials) --
__global__ __launch_bounds__(256) void ln4_kernel(const bf16_t* __restrict__ p,
                                                  const float* __restrict__ x,
                                                  const float* __restrict__ bproj,
                                                  const float* __restrict__ g,
                                                  const float* __restrict__ be,
                                                  bf16_t* __restrict__ outp) {
  const int row = blockIdx.x, t = threadIdx.x;
  const size_t PS = (size_t)4096 * 1024;
  const size_t off = (size_t)row * E_ + t * 4;
  float4 v = {0.f, 0.f, 0.f, 0.f};
#pragma unroll
  for (int z = 0; z < 4; ++z) {
    const ushort4 u = *(const ushort4*)(p + z * PS + off);
    v.x += bf2f(u.x); v.y += bf2f(u.y); v.z += bf2f(u.z); v.w += bf2f(u.w);
  }
  const float4 xr = *(const float4*)(x + off);
  const float4 bp = *(const float4*)(bproj + t * 4);
  v.x += xr.x + bp.x;
  v.y += xr.y + bp.y;
  v.z += xr.z + bp.z;
  v.w += xr.w + bp.w;
  ln_core(v, t, g, be, outp + (size_t)row * E_);
}

extern "C" void kernel_launch(void* const* d_in, const int* in_sizes, int n_in,
                              void* d_out, int out_size, void* d_ws, size_t ws_size,
                              hipStream_t stream) {
  (void)in_sizes; (void)n_in; (void)out_size;
  const float* x      = (const float*)d_in[0];
  const float* w_qkv  = (const float*)d_in[1];
  const float* b_qkv  = (const float*)d_in[2];
  const float* w_proj = (const float*)d_in[3];
  const float* b_proj = (const float*)d_in[4];
  const float* ln_g   = (const float*)d_in[5];
  const float* ln_b   = (const float*)d_in[6];
  const float* w1     = (const float*)d_in[7];
  const float* b1     = (const float*)d_in[8];
  const float* w2     = (const float*)d_in[9];
  const float* b2     = (const float*)d_in[10];
  float* out = (float*)d_out;
  char* ws = (char*)d_ws;
  const size_t MB = (size_t)1 << 20;
  // splitk layout (MB): [0,8) w2T | [8,16) w1T | [16,24) vtb->lnb | [24,30) wqkvT
  // | [30,32) wprojT | [32,40) attnb | [40,48) xb | [48,72) qkvb
  // proj parts bf16 z=4: [48,80) (qkvb dead) -> ln4 -> ffn1b [80,112)
  // ffn2 parts bf16 z=4: [16,48) (lnb/weightsT/attnb/xb dead) -> red4
  bf16_t* w2T    = (bf16_t*)(ws + 0 * MB);
  bf16_t* w1T    = (bf16_t*)(ws + 8 * MB);
  bf16_t* vtb    = (bf16_t*)(ws + 16 * MB);
  bf16_t* lnb    = (bf16_t*)(ws + 16 * MB);
  bf16_t* wqkvT  = (bf16_t*)(ws + 24 * MB);
  bf16_t* wprojT = (bf16_t*)(ws + 30 * MB);
  bf16_t* attnb  = (bf16_t*)(ws + 32 * MB);
  bf16_t* xb     = (bf16_t*)(ws + 40 * MB);
  bf16_t* qkvb   = (bf16_t*)(ws + 48 * MB);
  bf16_t* pparts = (bf16_t*)(ws + 48 * MB);  // 32MB bf16, z=4
  bf16_t* ffn1s  = (bf16_t*)(ws + 80 * MB);  // 32MB (splitk path)
  bf16_t* fparts = (bf16_t*)(ws + 16 * MB);  // 32MB bf16, z=4
  float*  hbuf   = (float*)(ws + 48 * MB);   // fallback
  bf16_t* ffn1f  = (bf16_t*)(ws + 48 * MB);  // fallback
  const bool splitk = ws_size >= 112 * MB;

  dim3 tb(32, 8);
  prep_kernel<<<16384, tb, 0, stream>>>(w_qkv, wqkvT, w_proj, wprojT, w1, w1T,
                                        w2, w2T, x, xb);

  gemm8<0><<<dim3(12, 16), 512, 0, stream>>>(xb, wqkvT, b_qkv, nullptr, nullptr, qkvb,
                                             4096, 3072, 1024, 16);

  vtrans_kernel<<<dim3(S_ / 32, 2, 32), tb, 0, stream>>>(qkvb, vtb);
  attn_kernel<<<dim3(32, 32), 128, 0, stream>>>(qkvb, vtb, attnb);

  if (splitk) {
    gemm8<4><<<dim3(4, 16, 4), 512, 0, stream>>>(attnb, wprojT, nullptr, nullptr,
                                                 nullptr, pparts, 4096, 1024, 1024, 4);
    ln4_kernel<<<4096, 256, 0, stream>>>(pparts, x, b_proj, ln_g, ln_b, lnb);
    gemm8<2><<<dim3(16, 16), 512, 0, stream>>>(lnb, w1T, b1, nullptr, nullptr, ffn1s,
                                               4096, 4096, 1024, 16);
    gemm8<4><<<dim3(4, 16, 4), 512, 0, stream>>>(ffn1s, w2T, nullptr, nullptr,
                                                 nullptr, fparts, 4096, 1024, 4096, 16);
    red4_kernel<<<4096, 256, 0, stream>>>(fparts, b2, out);
  } else {
    gemm8<1><<<dim3(4, 16), 512, 0, stream>>>(attnb, wprojT, b_proj, x, hbuf, nullptr,
                                              4096, 1024, 1024, 16);
    ln_kernel<<<4096, 256, 0, stream>>>(hbuf, ln_g, ln_b, lnb);
    gemm8<2><<<dim3(16, 16), 512, 0, stream>>>(lnb, w1T, b1, nullptr, nullptr, ffn1f,
                                               4096, 4096, 1024, 16);
    gemm8<3><<<dim3(4, 16), 512, 0, stream>>>(ffn1f, w2T, b2, nullptr, out, nullptr,
                                              4096, 1024, 4096, 64);
  }
}

// Round 15
// 237.697 us; speedup vs baseline: 1.3400x; 1.3400x over previous
//
#include <hip/hip_runtime.h>

#define B_ 2
#define S_ 2048
#define E_ 1024
#define H_ 16
#define DH_ 64
#define FF_ 4096

typedef unsigned short bf16_t;
typedef __attribute__((ext_vector_type(8))) short bfrag;
typedef __attribute__((ext_vector_type(4))) float f32x4;
typedef __attribute__((ext_vector_type(16))) float f32x16;
typedef __attribute__((ext_vector_type(4))) unsigned int u32x4;

__device__ __forceinline__ bf16_t f2bf(float x) {
  union { float f; unsigned u; } c; c.f = x;
  return (bf16_t)((c.u + 0x7fffu + ((c.u >> 16) & 1u)) >> 16);
}

__device__ __forceinline__ float bf2f(unsigned short u) {
  union { unsigned u; float f; } c; c.u = (unsigned)u << 16;
  return c.f;
}

__device__ __forceinline__ unsigned pkbf(float lo, float hi) {
  unsigned r;
  asm("v_cvt_pk_bf16_f32 %0, %1, %2" : "=v"(r) : "v"(lo), "v"(hi));
  return r;
}

__device__ __forceinline__ void gload16(const void* g, void* l) {
  __builtin_amdgcn_global_load_lds(
      (const __attribute__((address_space(1))) void*)g,
      (__attribute__((address_space(3))) void*)l, 16, 0, 0);
}

// ---- prep: 4 weight transposes (f32 -> bf16^T) + x f32->bf16 cvt, one grid ----
// bids: [0,3072) w_qkv | [3072,4096) w_proj | [4096,8192) w1 | [8192,12288) w2
//       | [12288,16384) x cvt
__global__ void prep_kernel(const float* __restrict__ s0, bf16_t* __restrict__ d0,
                            const float* __restrict__ s1, bf16_t* __restrict__ d1,
                            const float* __restrict__ s2, bf16_t* __restrict__ d2,
                            const float* __restrict__ s3, bf16_t* __restrict__ d3,
                            const float* __restrict__ xs, bf16_t* __restrict__ xd) {
  __shared__ float tile[32][33];
  const int bid = blockIdx.x;
  const int tx = threadIdx.x, ty = threadIdx.y;
  if (bid >= 12288) {
    const int i = (bid - 12288) * 256 + ty * 32 + tx;
    const float4 v = ((const float4*)xs)[i];
    union { bf16_t u[4]; uint2 uv; } o;
    o.u[0] = f2bf(v.x); o.u[1] = f2bf(v.y); o.u[2] = f2bf(v.z); o.u[3] = f2bf(v.w);
    *(uint2*)(xd + (size_t)i * 4) = o.uv;
    return;
  }
  const float* src; bf16_t* dst; int R, C, lid;
  if (bid < 3072)      { src = s0; dst = d0; R = 1024; C = 3072; lid = bid; }
  else if (bid < 4096) { src = s1; dst = d1; R = 1024; C = 1024; lid = bid - 3072; }
  else if (bid < 8192) { src = s2; dst = d2; R = 1024; C = 4096; lid = bid - 4096; }
  else                 { src = s3; dst = d3; R = 4096; C = 1024; lid = bid - 8192; }
  const int ncx = C >> 5;
  const int c0 = (lid % ncx) * 32, r0 = (lid / ncx) * 32;
#pragma unroll
  for (int i = 0; i < 32; i += 8)
    tile[ty + i][tx] = src[(size_t)(r0 + ty + i) * C + c0 + tx];
  __syncthreads();
#pragma unroll
  for (int i = 0; i < 32; i += 8)
    dst[(size_t)(c0 + ty + i) * R + r0 + tx] = f2bf(tile[tx][ty + i]);
}

// ---------------- V transpose per (b,h): [S][64] -> [64][S] bf16 ----------------
__global__ void vtrans_kernel(const bf16_t* __restrict__ qkv, bf16_t* __restrict__ vt) {
  const int bh = blockIdx.z;
  const int b = bh >> 4, h = bh & 15;
  const bf16_t* src = qkv + (size_t)b * S_ * 3 * E_ + (size_t)2 * H_ * S_ * DH_ +
                      (size_t)h * S_ * DH_;
  bf16_t* dst = vt + (size_t)bh * DH_ * S_;
  const int s0 = blockIdx.x * 32, d0 = blockIdx.y * 32;
  __shared__ bf16_t tile[32][33];
  const int tx = threadIdx.x, ty = threadIdx.y;
#pragma unroll
  for (int i = 0; i < 32; i += 8)
    tile[ty + i][tx] = src[(size_t)(s0 + ty + i) * DH_ + d0 + tx];
  __syncthreads();
#pragma unroll
  for (int i = 0; i < 32; i += 8)
    dst[(size_t)(d0 + ty + i) * S_ + s0 + tx] = tile[tx][ty + i];
}

// ================= 256x256 8-phase GEMM (m201 template, plain HIP) =============
// MODE 0: outB = bf16(acc + bias)            MODE 1: outF = acc + bias + resid
// MODE 2: outB = bf16(relu(acc + bias))      MODE 3: outF = acc + bias
// MODE 4: outB(partial z) = bf16(acc)        (split-K, bf16 partials)

__device__ __forceinline__ void stage_half(const bf16_t* __restrict__ G, int row0,
                                           int kbyte, int Kbytes, bf16_t* ldsreg,
                                           int w, int l) {
#pragma unroll
  for (int j = 0; j < 2; ++j) {
    const int chunk = j * 8 + w;                // wave-uniform
    const int r = chunk * 8 + (l >> 3);         // row within 128-row half (src only)
    const int slot = ((l & 7) ^ (r & 7)) << 4;  // pre-swizzled source slot
    const char* src = (const char*)G + (size_t)(row0 + r) * Kbytes + kbyte + slot;
    gload16(src, (char*)ldsreg + chunk * 1024);
  }
}

__device__ __forceinline__ bfrag ldfrag(const bf16_t* __restrict__ reg, int r, int ks,
                                        int l) {
  int cb = ks * 64 + ((l >> 4) << 4);
  cb ^= (r & 7) << 4;
  return *(const bfrag*)((const char*)reg + r * 128 + cb);
}

template <int MODE>
__global__ __launch_bounds__(512, 2) void gemm8(
    const bf16_t* __restrict__ A, const bf16_t* __restrict__ Bt,
    const float* __restrict__ bias, const float* __restrict__ resid,
    float* __restrict__ outF, bf16_t* __restrict__ outB,
    int M, int N, int K, int ktiles) {
  __shared__ __align__(16) bf16_t lds4[4][256 * 64];
  const int tid = threadIdx.x;
  const int w = tid >> 6, l = tid & 63;
  const int wr = (w >> 2) * 128, wc = (w & 3) * 64;
  const int m0t = blockIdx.y * 256, n0t = blockIdx.x * 256;
  const int Kb = K * 2;
  const int kt0 = (MODE == 4) ? (int)blockIdx.z * ktiles : 0;
  const int ktEnd = kt0 + ktiles;
  if (MODE == 4) outB += (size_t)blockIdx.z * (size_t)M * N;

  stage_half(A, m0t, kt0 * 128, Kb, lds4[0], w, l);
  stage_half(A, m0t + 128, kt0 * 128, Kb, lds4[0] + 8192, w, l);
  stage_half(Bt, n0t, kt0 * 128, Kb, lds4[1], w, l);
  stage_half(Bt, n0t + 128, kt0 * 128, Kb, lds4[1] + 8192, w, l);
  stage_half(Bt, n0t, (kt0 + 1) * 128, Kb, lds4[3], w, l);
  stage_half(Bt, n0t + 128, (kt0 + 1) * 128, Kb, lds4[3] + 8192, w, l);
  asm volatile("s_waitcnt vmcnt(4)" ::: "memory");
  __builtin_amdgcn_s_barrier();

  f32x4 acc[8][4] = {};
  const int fr = l & 15;

  for (int t2 = kt0; t2 < ktEnd; t2 += 2) {
#pragma unroll
    for (int d = 0; d < 2; ++d) {
      const bf16_t* Ar = lds4[d * 2];
      const bf16_t* Br = lds4[d * 2 + 1];
      int sa = t2 + 1 + d; if (sa >= ktEnd) sa = kt0;
      int sb = t2 + 2 + d; if (sb >= ktEnd) sb = kt0;
      bfrag bfr[4][2], afr[2][2];
#pragma unroll
      for (int p = 0; p < 4; ++p) {
        if (p == 0) {
#pragma unroll
          for (int n = 0; n < 4; ++n)
#pragma unroll
            for (int ks = 0; ks < 2; ++ks)
              bfr[n][ks] = ldfrag(Br, wc + n * 16 + fr, ks, l);
        }
#pragma unroll
        for (int mm = 0; mm < 2; ++mm)
#pragma unroll
          for (int ks = 0; ks < 2; ++ks)
            afr[mm][ks] = ldfrag(Ar, wr + p * 32 + mm * 16 + fr, ks, l);
        if (p == 0)      stage_half(A, m0t, sa * 128, Kb, lds4[(d ^ 1) * 2], w, l);
        else if (p == 1) stage_half(A, m0t + 128, sa * 128, Kb, lds4[(d ^ 1) * 2] + 8192, w, l);
        else if (p == 2) stage_half(Bt, n0t, sb * 128, Kb, lds4[d * 2 + 1], w, l);
        else             stage_half(Bt, n0t + 128, sb * 128, Kb, lds4[d * 2 + 1] + 8192, w, l);
        __builtin_amdgcn_s_barrier();
        asm volatile("s_waitcnt lgkmcnt(0)" ::: "memory");
        __builtin_amdgcn_sched_barrier(0);
        __builtin_amdgcn_s_setprio(1);
#pragma unroll
        for (int mm = 0; mm < 2; ++mm)
#pragma unroll
          for (int n = 0; n < 4; ++n)
#pragma unroll
            for (int ks = 0; ks < 2; ++ks)
              acc[p * 2 + mm][n] = __builtin_amdgcn_mfma_f32_16x16x32_bf16(
                  afr[mm][ks], bfr[n][ks], acc[p * 2 + mm][n], 0, 0, 0);
        __builtin_amdgcn_s_setprio(0);
        if (p == 3) asm volatile("s_waitcnt vmcnt(4)" ::: "memory");
        __builtin_amdgcn_s_barrier();
      }
    }
  }

  const int cr = (l >> 4) * 4, cc = l & 15;
#pragma unroll
  for (int n = 0; n < 4; ++n) {
    const int gc = n0t + wc + n * 16 + cc;
    const float bn = (MODE == 4) ? 0.f : bias[gc];
#pragma unroll
    for (int m = 0; m < 8; ++m) {
      const int gr0 = m0t + wr + m * 16 + cr;
#pragma unroll
      for (int j = 0; j < 4; ++j) {
        float v = acc[m][n][j] + bn;
        const size_t idx = (size_t)(gr0 + j) * N + gc;
        if (MODE == 1) v += resid[idx];
        if (MODE == 2) v = fmaxf(v, 0.f);
        if (MODE == 0 || MODE == 2 || MODE == 4) outB[idx] = f2bf(v);
        else outF[idx] = v;
      }
    }
  }
}

// ------ split-K reduce (bf16 partials): out = p0+p1+p2+p3 + bias (f32) ------
__global__ __launch_bounds__(256) void red4_kernel(const bf16_t* __restrict__ p,
                                                   const float* __restrict__ bias,
                                                   float* __restrict__ out) {
  const size_t i = ((size_t)blockIdx.x * 256 + threadIdx.x) * 4;
  const size_t PS = (size_t)4096 * 1024;
  float4 v = {0.f, 0.f, 0.f, 0.f};
#pragma unroll
  for (int z = 0; z < 4; ++z) {
    const ushort4 u = *(const ushort4*)(p + z * PS + i);
    v.x += bf2f(u.x); v.y += bf2f(u.y); v.z += bf2f(u.z); v.w += bf2f(u.w);
  }
  const float4 bb = *(const float4*)(bias + (i & 1023));
  v.x += bb.x; v.y += bb.y; v.z += bb.z; v.w += bb.w;
  *(float4*)(out + i) = v;
}

// ---------------- causal flash attention (r12/r13 optimum, reverted) ----------------
#define C1_ 0.0450842213f  // (1/32) * log2(e)

struct kf4 { bfrag k[4]; };

__device__ __forceinline__ kf4 loadK32(const bf16_t* __restrict__ Kp, int kv0,
                                       int lq32, int hi) {
  kf4 r;
#pragma unroll
  for (int c = 0; c < 4; ++c)
    r.k[c] = *(const bfrag*)&Kp[(size_t)(kv0 + lq32) * DH_ + c * 16 + hi * 8];
  return r;
}

template <bool MASK>
__device__ __forceinline__ void compute32(const kf4& s, const bf16_t* __restrict__ Vt,
                                          int kv0, const bfrag* qf, f32x16& o0,
                                          f32x16& o1, f32x16& lacc, float& m,
                                          int lq32, int hi) {
  const short onebf = (short)0x3F80;
  bfrag ones;
#pragma unroll
  for (int j = 0; j < 8; ++j) ones[j] = onebf;
  bfrag v00, v01, v10, v11;
  {
    const bf16_t* vr = &Vt[(size_t)lq32 * S_ + kv0 + hi * 8];
    v00 = *(const bfrag*)vr;
    v01 = *(const bfrag*)(vr + 16);
    const bf16_t* vr2 = &Vt[(size_t)(32 + lq32) * S_ + kv0 + hi * 8];
    v10 = *(const bfrag*)vr2;
    v11 = *(const bfrag*)(vr2 + 16);
  }
  f32x16 st;
#pragma unroll
  for (int j = 0; j < 16; ++j) st[j] = 0.f;
#pragma unroll
  for (int c = 0; c < 4; ++c)
    st = __builtin_amdgcn_mfma_f32_32x32x16_bf16(s.k[c], qf[c], st, 0, 0, 0);
  if (MASK) {
#pragma unroll
    for (int r = 0; r < 16; ++r) {
      const int kvloc = (r & 3) + 8 * (r >> 2) + 4 * hi;
      st[r] = (kvloc <= lq32) ? st[r] : -3.0e38f;
    }
  }
  float mx[8];
#pragma unroll
  for (int j = 0; j < 8; ++j) mx[j] = fmaxf(st[j], st[j + 8]);
#pragma unroll
  for (int stp = 4; stp >= 1; stp >>= 1)
#pragma unroll
    for (int j = 0; j < stp; ++j) mx[j] = fmaxf(mx[j], mx[j + stp]);
  float pm = fmaxf(mx[0], __shfl_xor(mx[0], 32));
  if (!__all(pm <= m + 128.0f)) {  // defer-max: P bounded by 2^(128*C1) ~ 54
    const float mn = fmaxf(m, pm);
    const float corr = exp2f((m - mn) * C1_);
    m = mn;
#pragma unroll
    for (int j = 0; j < 16; ++j) { o0[j] *= corr; o1[j] *= corr; lacc[j] *= corr; }
  }
  const float mc = m * C1_;
  float p[16];
#pragma unroll
  for (int j = 0; j < 16; ++j) p[j] = exp2f(__builtin_fmaf(st[j], C1_, -mc));
  unsigned wv[8], ov[8];
#pragma unroll
  for (int j = 0; j < 8; ++j) wv[j] = pkbf(p[2 * j], p[2 * j + 1]);
#pragma unroll
  for (int j = 0; j < 8; ++j) ov[j] = (unsigned)__shfl_xor((int)wv[j], 32);
  union { unsigned u[4]; bfrag f; } f0, f1;
  f0.u[0] = hi ? ov[2] : wv[0];  f0.u[1] = hi ? ov[3] : wv[1];
  f0.u[2] = hi ? wv[2] : ov[0];  f0.u[3] = hi ? wv[3] : ov[1];
  f1.u[0] = hi ? ov[6] : wv[4];  f1.u[1] = hi ? ov[7] : wv[5];
  f1.u[2] = hi ? wv[6] : ov[4];  f1.u[3] = hi ? wv[7] : ov[5];
  o0 = __builtin_amdgcn_mfma_f32_32x32x16_bf16(v00, f0.f, o0, 0, 0, 0);
  o1 = __builtin_amdgcn_mfma_f32_32x32x16_bf16(v10, f0.f, o1, 0, 0, 0);
  lacc = __builtin_amdgcn_mfma_f32_32x32x16_bf16(ones, f0.f, lacc, 0, 0, 0);
  o0 = __builtin_amdgcn_mfma_f32_32x32x16_bf16(v01, f1.f, o0, 0, 0, 0);
  o1 = __builtin_amdgcn_mfma_f32_32x32x16_bf16(v11, f1.f, o1, 0, 0, 0);
  lacc = __builtin_amdgcn_mfma_f32_32x32x16_bf16(ones, f1.f, lacc, 0, 0, 0);
}

__global__ __launch_bounds__(256, 2) void attn_kernel(const bf16_t* __restrict__ qkv,
                                                      const bf16_t* __restrict__ vt,
                                                      bf16_t* __restrict__ outp) {
  __shared__ unsigned short ot[4][32 * 72];
  const int tid = threadIdx.x;
  const int w = tid >> 6, l = tid & 63;
  const int lq32 = l & 31, hi = l >> 5;
  const int by = blockIdx.y;
  const int b = by >> 4, h = by & 15;
  const int qt = (by & 16) ? (15 - (int)blockIdx.x) : (int)blockIdx.x;
  const size_t bbase = (size_t)b * S_ * 3 * E_;
  const bf16_t* Q = qkv + bbase + (size_t)h * S_ * DH_;
  const bf16_t* Kp = Q + (size_t)H_ * S_ * DH_;
  const bf16_t* Vt = vt + (size_t)by * DH_ * S_;
  bf16_t* Og = outp + (size_t)by * S_ * DH_;
  const int q0w = qt * 128 + w * 32;

  bfrag qf[4];
#pragma unroll
  for (int c = 0; c < 4; ++c)
    qf[c] = *(const bfrag*)&Q[(size_t)(q0w + lq32) * DH_ + c * 16 + hi * 8];

  f32x16 o0, o1, lacc;
#pragma unroll
  for (int j = 0; j < 16; ++j) { o0[j] = 0.f; o1[j] = 0.f; lacc[j] = 0.f; }
  float m = -3.0e38f;

  const int nsteps = q0w >> 5;  // full 32-kv steps before the diagonal
  kf4 kcur = loadK32(Kp, 0, lq32, hi);
  for (int s = 0; s < nsteps; ++s) {
    kf4 knxt = loadK32(Kp, (s + 1) * 32, lq32, hi);  // last iter = diagonal K
    compute32<false>(kcur, Vt, s * 32, qf, o0, o1, lacc, m, lq32, hi);
    kcur = knxt;
  }
  compute32<true>(kcur, Vt, q0w, qf, o0, o1, lacc, m, lq32, hi);

  // epilogue: O^T regs -> LDS [q][d] (stride 72) -> coalesced [s][d] global
  const float linv = 1.0f / lacc[0];
  unsigned short* otw = ot[w];
#pragma unroll
  for (int t = 0; t < 2; ++t) {
    const f32x16& oo = t ? o1 : o0;
#pragma unroll
    for (int g = 0; g < 4; ++g) {
      const int d = t * 32 + g * 8 + hi * 4;
      uint2 v;
      v.x = pkbf(oo[g * 4 + 0] * linv, oo[g * 4 + 1] * linv);
      v.y = pkbf(oo[g * 4 + 2] * linv, oo[g * 4 + 3] * linv);
      *(uint2*)&otw[lq32 * 72 + d] = v;
    }
  }
  asm volatile("s_waitcnt lgkmcnt(0)" ::: "memory");
  const int q = l >> 1, hh = l & 1;
#pragma unroll
  for (int i = 0; i < 4; ++i) {
    u32x4 v = *(const u32x4*)&otw[q * 72 + hh * 32 + i * 8];
    *(u32x4*)&Og[(size_t)(q0w + q) * DH_ + hh * 32 + i * 8] = v;
  }
}

// ---------------- LayerNorm (plain): f32 in -> bf16 ----------------
__device__ __forceinline__ void ln_core(float4 v, int t, const float* g,
                                        const float* be, bf16_t* orow) {
  float s = v.x + v.y + v.z + v.w;
  float q = v.x * v.x + v.y * v.y + v.z * v.z + v.w * v.w;
#pragma unroll
  for (int d = 1; d < 64; d <<= 1) { s += __shfl_xor(s, d); q += __shfl_xor(q, d); }
  __shared__ float red[8];
  const int w = t >> 6;
  if ((t & 63) == 0) { red[w] = s; red[4 + w] = q; }
  __syncthreads();
  s = red[0] + red[1] + red[2] + red[3];
  q = red[4] + red[5] + red[6] + red[7];
  const float mu = s * (1.f / E_);
  const float var = q * (1.f / E_) - mu * mu;
  const float rs = rsqrtf(var + 1e-5f);
  const float4 gg = ((const float4*)g)[t];
  const float4 bb = ((const float4*)be)[t];
  union { bf16_t u[4]; uint2 uv; } o;
  o.u[0] = f2bf((v.x - mu) * rs * gg.x + bb.x);
  o.u[1] = f2bf((v.y - mu) * rs * gg.y + bb.y);
  o.u[2] = f2bf((v.z - mu) * rs * gg.z + bb.z);
  o.u[3] = f2bf((v.w - mu) * rs * gg.w + bb.w);
  *(uint2*)(orow + t * 4) = o.uv;
}

__global__ __launch_bounds__(256) void ln_kernel(const float* __restrict__ hin,
                                                 const float* __restrict__ g,
                                                 const float* __restrict__ be,
                                                 bf16_t* __restrict__ outp) {
  const int row = blockIdx.x, t = threadIdx.x;
  const float4 v = ((const float4*)(hin + (size_t)row * E_))[t];
  ln_core(v, t, g, be, outp + (size_t)row * E_);
}

// -- LN fused with proj split-K(z=4) reduce (bf16 partials) --
__global__ __launch_bounds__(256) void ln4_kernel(const bf16_t* __restrict__ p,
                                                  const float* __restrict__ x,
                                                  const float* __restrict__ bproj,
                                                  const float* __restrict__ g,
                                                  const float* __restrict__ be,
                                                  bf16_t* __restrict__ outp) {
  const int row = blockIdx.x, t = threadIdx.x;
  const size_t PS = (size_t)4096 * 1024;
  const size_t off = (size_t)row * E_ + t * 4;
  float4 v = {0.f, 0.f, 0.f, 0.f};
#pragma unroll
  for (int z = 0; z < 4; ++z) {
    const ushort4 u = *(const ushort4*)(p + z * PS + off);
    v.x += bf2f(u.x); v.y += bf2f(u.y); v.z += bf2f(u.z); v.w += bf2f(u.w);
  }
  const float4 xr = *(const float4*)(x + off);
  const float4 bp = *(const float4*)(bproj + t * 4);
  v.x += xr.x + bp.x;
  v.y += xr.y + bp.y;
  v.z += xr.z + bp.z;
  v.w += xr.w + bp.w;
  ln_core(v, t, g, be, outp + (size_t)row * E_);
}

extern "C" void kernel_launch(void* const* d_in, const int* in_sizes, int n_in,
                              void* d_out, int out_size, void* d_ws, size_t ws_size,
                              hipStream_t stream) {
  (void)in_sizes; (void)n_in; (void)out_size;
  const float* x      = (const float*)d_in[0];
  const float* w_qkv  = (const float*)d_in[1];
  const float* b_qkv  = (const float*)d_in[2];
  const float* w_proj = (const float*)d_in[3];
  const float* b_proj = (const float*)d_in[4];
  const float* ln_g   = (const float*)d_in[5];
  const float* ln_b   = (const float*)d_in[6];
  const float* w1     = (const float*)d_in[7];
  const float* b1     = (const float*)d_in[8];
  const float* w2     = (const float*)d_in[9];
  const float* b2     = (const float*)d_in[10];
  float* out = (float*)d_out;
  char* ws = (char*)d_ws;
  const size_t MB = (size_t)1 << 20;
  // splitk layout (MB): [0,8) w2T | [8,16) w1T | [16,24) vtb->lnb | [24,30) wqkvT
  // | [30,32) wprojT | [32,40) attnb | [40,48) xb | [48,72) qkvb
  // proj parts bf16 z=4: [48,80) (qkvb dead) -> ln4 -> ffn1b [80,112)
  // ffn2 parts bf16 z=4: [16,48) (lnb/weightsT/attnb/xb dead) -> red4
  bf16_t* w2T    = (bf16_t*)(ws + 0 * MB);
  bf16_t* w1T    = (bf16_t*)(ws + 8 * MB);
  bf16_t* vtb    = (bf16_t*)(ws + 16 * MB);
  bf16_t* lnb    = (bf16_t*)(ws + 16 * MB);
  bf16_t* wqkvT  = (bf16_t*)(ws + 24 * MB);
  bf16_t* wprojT = (bf16_t*)(ws + 30 * MB);
  bf16_t* attnb  = (bf16_t*)(ws + 32 * MB);
  bf16_t* xb     = (bf16_t*)(ws + 40 * MB);
  bf16_t* qkvb   = (bf16_t*)(ws + 48 * MB);
  bf16_t* pparts = (bf16_t*)(ws + 48 * MB);  // 32MB bf16, z=4
  bf16_t* ffn1s  = (bf16_t*)(ws + 80 * MB);  // 32MB (splitk path)
  bf16_t* fparts = (bf16_t*)(ws + 16 * MB);  // 32MB bf16, z=4
  float*  hbuf   = (float*)(ws + 48 * MB);   // fallback
  bf16_t* ffn1f  = (bf16_t*)(ws + 48 * MB);  // fallback
  const bool splitk = ws_size >= 112 * MB;

  dim3 tb(32, 8);
  prep_kernel<<<16384, tb, 0, stream>>>(w_qkv, wqkvT, w_proj, wprojT, w1, w1T,
                                        w2, w2T, x, xb);

  gemm8<0><<<dim3(12, 16), 512, 0, stream>>>(xb, wqkvT, b_qkv, nullptr, nullptr, qkvb,
                                             4096, 3072, 1024, 16);

  vtrans_kernel<<<dim3(S_ / 32, 2, 32), tb, 0, stream>>>(qkvb, vtb);
  attn_kernel<<<dim3(16, 32), 256, 0, stream>>>(qkvb, vtb, attnb);

  if (splitk) {
    gemm8<4><<<dim3(4, 16, 4), 512, 0, stream>>>(attnb, wprojT, nullptr, nullptr,
                                                 nullptr, pparts, 4096, 1024, 1024, 4);
    ln4_kernel<<<4096, 256, 0, stream>>>(pparts, x, b_proj, ln_g, ln_b, lnb);
    gemm8<2><<<dim3(16, 16), 512, 0, stream>>>(lnb, w1T, b1, nullptr, nullptr, ffn1s,
                                               4096, 4096, 1024, 16);
    gemm8<4><<<dim3(4, 16, 4), 512, 0, stream>>>(ffn1s, w2T, nullptr, nullptr,
                                                 nullptr, fparts, 4096, 1024, 4096, 16);
    red4_kernel<<<4096, 256, 0, stream>>>(fparts, b2, out);
  } else {
    gemm8<1><<<dim3(4, 16), 512, 0, stream>>>(attnb, wprojT, b_proj, x, hbuf, nullptr,
                                              4096, 1024, 1024, 16);
    ln_kernel<<<4096, 256, 0, stream>>>(hbuf, ln_g, ln_b, lnb);
    gemm8<2><<<dim3(16, 16), 512, 0, stream>>>(lnb, w1T, b1, nullptr, nullptr, ffn1f,
                                               4096, 4096, 1024, 16);
    gemm8<3><<<dim3(4, 16), 512, 0, stream>>>(ffn1f, w2T, b2, nullptr, out, nullptr,
                                              4096, 1024, 4096, 64);
  }
}